// Round 7
// baseline (1410.410 us; speedup 1.0000x reference)
//
#include <hip/hip_runtime.h>
#include <hip/hip_cooperative_groups.h>

namespace cg = cooperative_groups;

// Problem constants
#define N_ANCH   589824     // 256*256*9
#define TOPK     12000
#define KPAD     12032      // 188*64
#define NW       188        // mask words per row
#define OUTN     2000
#define CAP      32768      // candidate buffer capacity
#define GRID     1024       // cooperative grid (4 blocks/CU guaranteed)

typedef unsigned long long u64;

// 9 base anchors (ratio-major, scale-minor), widths/heights (x1-x0+1)
__constant__ float c_aw[9] = {184.f, 368.f, 736.f, 128.f, 256.f, 512.f,  88.f, 176.f, 352.f};
__constant__ float c_ah[9] = { 96.f, 192.f, 384.f, 128.f, 256.f, 512.f, 176.f, 352.f, 704.f};

// Decode one anchor's proposal box exactly like the (non-fused fp32) reference.
__device__ __forceinline__ void decode_one(int i, const float4* __restrict__ delta,
                                           float4* box, bool* valid) {
#pragma clang fp contract(off)
    int a    = i % 9;
    int cell = i / 9;
    int gx = cell & 255;
    int gy = cell >> 8;
    float w = c_aw[a], h = c_ah[a];
    float cx = (float)gx * 16.0f + 8.0f;
    float cy = (float)gy * 16.0f + 8.0f;
    float4 d = delta[i];
    float pcx = d.x * w + cx;
    float pcy = d.y * h + cy;
    float pw  = expf(d.z) * w;
    float ph  = expf(d.w) * h;
    float x0 = fminf(fmaxf(pcx - 0.5f * pw, 0.f), 4096.f);
    float y0 = fminf(fmaxf(pcy - 0.5f * ph, 0.f), 4096.f);
    float x1 = fminf(fmaxf(pcx + 0.5f * pw, 0.f), 4096.f);
    float y1 = fminf(fmaxf(pcy + 0.5f * ph, 0.f), 4096.f);
    *box = make_float4(x0, y0, x1, y1);
    *valid = (x1 - x0 >= 16.f) && (y1 - y0 >= 16.f);
}

__global__ __launch_bounds__(256, 4) void k_fused(
        const float4* __restrict__ delta, const float2* __restrict__ score,
        unsigned* __restrict__ ukey, unsigned* __restrict__ hist1,
        unsigned* __restrict__ hist2, unsigned* __restrict__ ctrl,
        u64* __restrict__ cand, float4* __restrict__ sbox,
        u64* __restrict__ mask, float4* __restrict__ out) {
    cg::grid_group g = cg::this_grid();
    int tid = threadIdx.x;
    int bid = blockIdx.x;
    int lane = tid & 63;
    int wave = tid >> 6;

    __shared__ unsigned lh[256];
    __shared__ unsigned ss[256];
    __shared__ u64 tile[256];
    __shared__ float4 cbox[256];
    __shared__ unsigned s_sc[4];
    __shared__ u64 s_rwsh[2];

    // ---------- phase 1: decode + key + LDS-aggregated level-1 histogram ----------
    lh[tid] = 0u;
    __syncthreads();
    for (int i = bid * 256 + tid; i < N_ANCH; i += GRID * 256) {
        float4 box; bool valid;
        decode_one(i, delta, &box, &valid);
        unsigned u = 0u;
        if (valid) {
            unsigned b = __float_as_uint(score[i].y);
            u = (b & 0x80000000u) ? ~b : (b | 0x80000000u);  // order-preserving; 0 = dead
        }
        ukey[i] = u;
        atomicAdd(&lh[u >> 24], 1u);
    }
    __syncthreads();
    if (lh[tid]) atomicAdd(&hist1[tid], lh[tid]);
    g.sync();

    // ---------- phase 2: b1 (per-block redundant scan) + level-2 histogram ----------
    ss[tid] = hist1[tid];
    lh[tid] = 0u;
    if (tid == 0) s_sc[0] = 0u;
    __syncthreads();
    for (int d = 1; d < 256; d <<= 1) {
        unsigned v = (tid + d < 256) ? ss[tid + d] : 0u;
        __syncthreads();
        ss[tid] += v;
        __syncthreads();
    }
    if (ss[tid] >= (unsigned)TOPK && (tid == 255 || ss[tid + 1] < (unsigned)TOPK))
        s_sc[0] = (unsigned)tid;
    __syncthreads();
    unsigned b1 = s_sc[0];
    for (int i = bid * 256 + tid; i < N_ANCH; i += GRID * 256) {
        unsigned u = ukey[i];
        if ((u >> 24) == b1) atomicAdd(&lh[(u >> 16) & 255u], 1u);
    }
    __syncthreads();
    if (lh[tid]) atomicAdd(&hist2[tid], lh[tid]);
    g.sync();

    // ---------- phase 3: P (two redundant scans) + compact ----------
    ss[tid] = hist1[tid];
    if (tid == 0) { s_sc[0] = 0u; s_sc[1] = 0u; }
    __syncthreads();
    for (int d = 1; d < 256; d <<= 1) {
        unsigned v = (tid + d < 256) ? ss[tid + d] : 0u;
        __syncthreads();
        ss[tid] += v;
        __syncthreads();
    }
    if (ss[tid] >= (unsigned)TOPK && (tid == 255 || ss[tid + 1] < (unsigned)TOPK)) {
        s_sc[0] = (unsigned)tid;
        s_sc[1] = (tid == 255) ? 0u : ss[tid + 1];
    }
    __syncthreads();
    b1 = s_sc[0];
    unsigned ab1 = s_sc[1];
    ss[tid] = hist2[tid];
    if (tid == 0) s_sc[2] = (b1 << 8);            // fallback b2 = 0 (take-all)
    __syncthreads();
    for (int d = 1; d < 256; d <<= 1) {
        unsigned v = (tid + d < 256) ? ss[tid + d] : 0u;
        __syncthreads();
        ss[tid] += v;
        __syncthreads();
    }
    unsigned target = (unsigned)TOPK - ab1;
    if (ss[tid] >= target && (tid == 255 || ss[tid + 1] < target))
        s_sc[2] = (b1 << 8) | (unsigned)tid;
    __syncthreads();
    unsigned P = s_sc[2];
    for (int i = bid * 256 + tid; i < N_ANCH; i += GRID * 256) {
        unsigned u = ukey[i];
        bool pred = (u != 0u) && ((u >> 16) >= P);
        u64 m = __ballot(pred);
        if (m) {
            int leader = __ffsll(m) - 1;
            unsigned base = 0;
            if (lane == leader) base = atomicAdd(&ctrl[3], (unsigned)__popcll(m));
            base = __shfl(base, leader);
            if (pred) {
                u64 below = m & ((1ull << lane) - 1ull);
                unsigned pos = base + (unsigned)__popcll(below);
                if (pos < CAP) cand[pos] = ((u64)u << 32) | (unsigned)(~i);
            }
        }
    }
    g.sync();

    // ---------- phase 4: exact rank + decode into sbox ----------
    unsigned cnt = ctrl[3];
    int C = (int)(cnt < (unsigned)CAP ? cnt : (unsigned)CAP);
    if (bid * 256 < C) {                           // block-uniform participation
        int t = bid * 256 + tid;
        u64 mykey = (t < C) ? cand[t] : ~0ull;
        int rank = 0;
        for (int j0 = 0; j0 < C; j0 += 256) {
            int j = j0 + tid;
            tile[tid] = (j < C) ? cand[j] : 0ull;
            __syncthreads();
            int lim = (C - j0 < 256) ? (C - j0) : 256;
            #pragma unroll 4
            for (int jj = 0; jj < lim; ++jj) rank += (tile[jj] > mykey) ? 1 : 0;
            __syncthreads();
        }
        if (t < C && rank < TOPK) {
            int idx = (int)(~(unsigned)mykey);
            float4 box; bool v;
            decode_one(idx, delta, &box, &v);
            sbox[rank] = box;
        }
    }
    g.sync();

    // ---------- phase 5: suppression bitmask, ROW-major mask[r*NW + cb] ----------
    // Tile = (rb, 4 cbs); wave w handles cb = cb0 + w. Upper triangle only.
    for (unsigned tix = (unsigned)bid; tix < 47u * 188u; tix += GRID) {
        int rb = (int)(tix / 47u);
        int cb0 = (int)(tix % 47u) * 4;
        if (cb0 + 3 < rb) continue;                // block-uniform skip
        __syncthreads();
        cbox[tid] = sbox[cb0 * 64 + tid];          // 4 strips of 64 boxes
        __syncthreads();
        int cb = cb0 + wave;
        if (cb >= rb) {
            int r = rb * 64 + lane;
            float4 me = sbox[r];
            float areaMe = (me.z - me.x) * (me.w - me.y);
            u64 bits = 0ull;
            for (int j = 0; j < 64; ++j) {
                float4 o = cbox[wave * 64 + j];    // wave-broadcast read
                float xx0 = fmaxf(me.x, o.x);
                float yy0 = fmaxf(me.y, o.y);
                float xx1 = fminf(me.z, o.z);
                float yy1 = fminf(me.w, o.w);
                float iw = fmaxf(xx1 - xx0, 0.f);
                float ih = fmaxf(yy1 - yy0, 0.f);
                float inter = iw * ih;
                float areaO = (o.z - o.x) * (o.w - o.y);
                float denom = fmaxf(areaMe + areaO - inter, 1e-8f);
                float iou = inter / denom;
                if (iou > 0.7f && (cb * 64 + j) != r) bits |= (1ull << j);
            }
            mask[(size_t)r * NW + cb] = bits;
        }
    }
    g.sync();

    // ---------- phase 6: blocked greedy reduce (block 0 only) ----------
    if (bid != 0) return;

    int nvalid = C < TOPK ? C : TOPK;
    int nblocks = (nvalid + 63) >> 6;

    u64 removed_t = ~0ull;                         // thread t owns column word t
    if (tid < NW) {
        long long lo = (long long)tid * 64;
        if (lo + 64 <= (long long)nvalid) removed_t = 0ull;
        else if (lo < (long long)nvalid)
            removed_t = ~((1ull << (unsigned)(nvalid - lo)) - 1ull);
    }

    int nk = 0;
    u64 p0=0,p1=0,p2=0,p3=0,p4=0,p5=0,p6=0,p7=0;
    u64 p8=0,p9=0,p10=0,p11=0,p12=0,p13=0,p14=0,p15=0;
    u64 dgnext = 0ull;
    if (nblocks > 0) dgnext = mask[(size_t)lane * NW + 0];  // diag of block 0

    for (int b = 0; b < nblocks; ++b) {
        // fold pending OR loads (issued last iteration; coalesced strips)
        removed_t |= ((p0|p1)|(p2|p3)) | ((p4|p5)|(p6|p7));
        removed_t |= ((p8|p9)|(p10|p11)) | ((p12|p13)|(p14|p15));
        p0=p1=p2=p3=p4=p5=p6=p7=0ull;
        p8=p9=p10=p11=p12=p13=p14=p15=0ull;
        u64 dg = dgnext;
        if (tid == b) s_rwsh[b & 1] = removed_t;   // word b now final
        __syncthreads();
        u64 rw = s_rwsh[b & 1];
        if (b + 1 < nblocks)                       // prefetch next diag (regs, all waves)
            dgnext = mask[(size_t)((b + 1) * 64 + lane) * NW + (b + 1)];

        // resolve via IoU symmetry: lane tests bits of ITS OWN diag word
        bool alive = ((rw >> lane) & 1ull) == 0ull;
        int budget = OUTN - nk;
        u64 keptmask = 0ull;
        int kc = 0;
        while (kc < budget) {
            u64 m = __ballot(alive);
            if (!m) break;
            int j = __ffsll(m) - 1;                // uniform
            keptmask |= (1ull << j);
            ++kc;
            alive = alive && (lane != j) && (((dg >> j) & 1ull) == 0ull);
        }

        if (wave == 0 && ((keptmask >> lane) & 1ull)) {
            int pos = nk + (int)__popcll(keptmask & ((1ull << lane) - 1ull));
            out[pos] = sbox[b * 64 + lane];
        }
        nk += kc;
        if (nk >= OUTN) break;

        // issue OR loads for next-iteration fold: mask[r*NW + tid] is
        // CONTIGUOUS across threads (coalesced strip per kept row)
        if (kc > 0 && tid > b && tid < NW) {
            const u64* mt = mask + tid;
            u64 km = keptmask;
            int jf = __ffsll(km) - 1;
            int i0 = jf;                          km &= km - 1;
            int i1  = km ? __ffsll(km) - 1 : jf;  km &= km - 1;
            int i2  = km ? __ffsll(km) - 1 : jf;  km &= km - 1;
            int i3  = km ? __ffsll(km) - 1 : jf;  km &= km - 1;
            int i4  = km ? __ffsll(km) - 1 : jf;  km &= km - 1;
            int i5  = km ? __ffsll(km) - 1 : jf;  km &= km - 1;
            int i6  = km ? __ffsll(km) - 1 : jf;  km &= km - 1;
            int i7  = km ? __ffsll(km) - 1 : jf;  km &= km - 1;
            int i8  = km ? __ffsll(km) - 1 : jf;  km &= km - 1;
            int i9  = km ? __ffsll(km) - 1 : jf;  km &= km - 1;
            int i10 = km ? __ffsll(km) - 1 : jf;  km &= km - 1;
            int i11 = km ? __ffsll(km) - 1 : jf;  km &= km - 1;
            int i12 = km ? __ffsll(km) - 1 : jf;  km &= km - 1;
            int i13 = km ? __ffsll(km) - 1 : jf;  km &= km - 1;
            int i14 = km ? __ffsll(km) - 1 : jf;  km &= km - 1;
            int i15 = km ? __ffsll(km) - 1 : jf;  km &= km - 1;
            size_t rb8 = (size_t)b * 64 * NW;
            p0  = mt[rb8 + (size_t)i0  * NW];
            p1  = mt[rb8 + (size_t)i1  * NW];
            p2  = mt[rb8 + (size_t)i2  * NW];
            p3  = mt[rb8 + (size_t)i3  * NW];
            p4  = mt[rb8 + (size_t)i4  * NW];
            p5  = mt[rb8 + (size_t)i5  * NW];
            p6  = mt[rb8 + (size_t)i6  * NW];
            p7  = mt[rb8 + (size_t)i7  * NW];
            p8  = mt[rb8 + (size_t)i8  * NW];
            p9  = mt[rb8 + (size_t)i9  * NW];
            p10 = mt[rb8 + (size_t)i10 * NW];
            p11 = mt[rb8 + (size_t)i11 * NW];
            p12 = mt[rb8 + (size_t)i12 * NW];
            p13 = mt[rb8 + (size_t)i13 * NW];
            p14 = mt[rb8 + (size_t)i14 * NW];
            p15 = mt[rb8 + (size_t)i15 * NW];
            while (km) {                           // rare: kc > 16
                int j = __ffsll(km) - 1; km &= km - 1;
                removed_t |= mt[rb8 + (size_t)j * NW];
            }
        }
    }

    float4 z = make_float4(0.f, 0.f, 0.f, 0.f);
    for (int p = nk + tid; p < OUTN; p += 256) out[p] = z;
}

extern "C" void kernel_launch(void* const* d_in, const int* in_sizes, int n_in,
                              void* d_out, int out_size, void* d_ws, size_t ws_size,
                              hipStream_t stream) {
    const float4* delta = (const float4*)d_in[0];
    const float2* score = (const float2*)d_in[1];
    char* ws = (char*)d_ws;

    // Workspace layout (bytes)
    unsigned* ukey  = (unsigned*)(ws + 0);         // N_ANCH u32
    u64*      cand  = (u64*)(ws + 2359296);        // CAP u64
    unsigned* hist1 = (unsigned*)(ws + 2621440);   // 256 u32  -- memset region start
    unsigned* hist2 = (unsigned*)(ws + 2622464);   // 256 u32
    unsigned* ctrl  = (unsigned*)(ws + 2623488);   // 16 u32
    float4*   sbox  = (float4*)(ws + 2623552);     // KPAD float4 (zeroed: pad ranks)
    u64*      mask  = (u64*)(ws + 2816064);        // KPAD*NW u64, ROW-major
    float4*   outp  = (float4*)d_out;

    hipMemsetAsync(ws + 2621440, 0, 194624, stream);   // hist1+hist2+ctrl+sbox

    void* args[] = {&delta, &score, &ukey, &hist1, &hist2, &ctrl,
                    &cand, &sbox, &mask, &outp};
    hipLaunchCooperativeKernel((const void*)k_fused, dim3(GRID), dim3(256),
                               args, 0, stream);
}

// Round 9
// 1165.849 us; speedup vs baseline: 1.2098x; 1.2098x over previous
//
#include <hip/hip_runtime.h>

// Problem constants
#define N_ANCH   589824     // 256*256*9
#define TOPK     12000
#define KPAD     12032      // 188*64
#define NW       188        // mask words per row
#define OUTN     2000
#define CAP      32768      // candidate buffer capacity
#define GRID     256        // cooperative grid: 1 block/CU

typedef unsigned long long u64;

// 9 base anchors (ratio-major, scale-minor), widths/heights (x1-x0+1)
__constant__ float c_aw[9] = {184.f, 368.f, 736.f, 128.f, 256.f, 512.f,  88.f, 176.f, 352.f};
__constant__ float c_ah[9] = { 96.f, 192.f, 384.f, 128.f, 256.f, 512.f, 176.f, 352.f, 704.f};

__device__ __forceinline__ void decode_one(int i, const float4* __restrict__ delta,
                                           float4* box, bool* valid) {
#pragma clang fp contract(off)
    int a    = i % 9;
    int cell = i / 9;
    int gx = cell & 255;
    int gy = cell >> 8;
    float w = c_aw[a], h = c_ah[a];
    float cx = (float)gx * 16.0f + 8.0f;
    float cy = (float)gy * 16.0f + 8.0f;
    float4 d = delta[i];
    float pcx = d.x * w + cx;
    float pcy = d.y * h + cy;
    float pw  = expf(d.z) * w;
    float ph  = expf(d.w) * h;
    float x0 = fminf(fmaxf(pcx - 0.5f * pw, 0.f), 4096.f);
    float y0 = fminf(fmaxf(pcy - 0.5f * ph, 0.f), 4096.f);
    float x1 = fminf(fmaxf(pcx + 0.5f * pw, 0.f), 4096.f);
    float y1 = fminf(fmaxf(pcy + 0.5f * ph, 0.f), 4096.f);
    *box = make_float4(x0, y0, x1, y1);
    *valid = (x1 - x0 >= 16.f) && (y1 - y0 >= 16.f);
}

// Lightweight agent-scope grid barrier. Slot counters zeroed by host memset.
__device__ __forceinline__ void gbar(unsigned* bar, int slot, bool wait) {
    __syncthreads();                     // drains this block's vmem
    if (threadIdx.x == 0) {
        __threadfence();                 // release (wbL2 on gfx9xx agent scope)
        atomicAdd(&bar[slot * 32], 1u);
        if (wait) {
            while (__hip_atomic_load(&bar[slot * 32], __ATOMIC_RELAXED,
                                     __HIP_MEMORY_SCOPE_AGENT) < (unsigned)GRID)
                __builtin_amdgcn_s_sleep(8);
            __threadfence();             // acquire (invL2)
        }
    }
    __syncthreads();
}

__global__ __launch_bounds__(256) void k_fused(
        const float4* __restrict__ delta, const float2* __restrict__ score,
        unsigned* __restrict__ ukey, unsigned* __restrict__ hist1,
        unsigned* __restrict__ hist2, unsigned* __restrict__ ctrl,
        unsigned* __restrict__ bar, u64* __restrict__ cand,
        float4* __restrict__ sbox, u64* __restrict__ mask,
        float4* __restrict__ out) {
    int tid = threadIdx.x;
    int bid = blockIdx.x;
    int lane = tid & 63;
    int wave = tid >> 6;

    __shared__ unsigned lh[256];
    __shared__ unsigned ss[256];
    __shared__ u64 tile[256];
    __shared__ float4 cbox[256];
    __shared__ unsigned s_u[4];
    __shared__ u64 s_rw[2];

    // ---------- P1: decode + key + LDS-aggregated level-1 histogram (bits 31:24) ----------
    lh[tid] = 0u;
    __syncthreads();
    for (int i = bid * 256 + tid; i < N_ANCH; i += GRID * 256) {   // 9 iters
        float4 box; bool valid;
        decode_one(i, delta, &box, &valid);
        unsigned u = 0u;
        if (valid) {
            unsigned b = __float_as_uint(score[i].y);
            u = (b & 0x80000000u) ? ~b : (b | 0x80000000u);  // order-preserving; 0 = dead
        }
        ukey[i] = u;
        atomicAdd(&lh[u >> 24], 1u);
    }
    __syncthreads();
    if (lh[tid]) atomicAdd(&hist1[tid], lh[tid]);
    gbar(bar, 0, true);

    // ---------- P2: b1 (per-block redundant scan) + level-2 histogram ----------
    ss[tid] = hist1[tid];
    lh[tid] = 0u;
    if (tid == 0) s_u[0] = 0u;
    __syncthreads();
    for (int d = 1; d < 256; d <<= 1) {
        unsigned v = (tid + d < 256) ? ss[tid + d] : 0u;
        __syncthreads();
        ss[tid] += v;
        __syncthreads();
    }
    if (ss[tid] >= (unsigned)TOPK && (tid == 255 || ss[tid + 1] < (unsigned)TOPK))
        s_u[0] = (unsigned)tid;
    __syncthreads();
    unsigned b1 = s_u[0];
    for (int i = bid * 256 + tid; i < N_ANCH; i += GRID * 256) {
        unsigned u = ukey[i];
        if ((u >> 24) == b1) atomicAdd(&lh[(u >> 16) & 255u], 1u);
    }
    __syncthreads();
    if (lh[tid]) atomicAdd(&hist2[tid], lh[tid]);
    gbar(bar, 1, true);

    // ---------- P3: P (two redundant scans) + compact ----------
    ss[tid] = hist1[tid];
    if (tid == 0) { s_u[0] = 0u; s_u[1] = 0u; }
    __syncthreads();
    for (int d = 1; d < 256; d <<= 1) {
        unsigned v = (tid + d < 256) ? ss[tid + d] : 0u;
        __syncthreads();
        ss[tid] += v;
        __syncthreads();
    }
    if (ss[tid] >= (unsigned)TOPK && (tid == 255 || ss[tid + 1] < (unsigned)TOPK)) {
        s_u[0] = (unsigned)tid;
        s_u[1] = (tid == 255) ? 0u : ss[tid + 1];
    }
    __syncthreads();
    b1 = s_u[0];
    unsigned ab1 = s_u[1];
    ss[tid] = hist2[tid];
    if (tid == 0) s_u[2] = (b1 << 8);            // fallback b2 = 0 (take-all)
    __syncthreads();
    for (int d = 1; d < 256; d <<= 1) {
        unsigned v = (tid + d < 256) ? ss[tid + d] : 0u;
        __syncthreads();
        ss[tid] += v;
        __syncthreads();
    }
    unsigned target = (unsigned)TOPK - ab1;
    if (ss[tid] >= target && (tid == 255 || ss[tid + 1] < target))
        s_u[2] = (b1 << 8) | (unsigned)tid;
    __syncthreads();
    unsigned P = s_u[2];
    for (int i = bid * 256 + tid; i < N_ANCH; i += GRID * 256) {
        unsigned u = ukey[i];
        bool pred = (u != 0u) && ((u >> 16) >= P);
        u64 m = __ballot(pred);
        if (m) {
            int leader = __ffsll(m) - 1;
            unsigned base = 0;
            if (lane == leader) base = atomicAdd(&ctrl[3], (unsigned)__popcll(m));
            base = __shfl(base, leader);
            if (pred) {
                u64 below = m & ((1ull << lane) - 1ull);
                unsigned pos = base + (unsigned)__popcll(below);
                if (pos < CAP) cand[pos] = ((u64)u << 32) | (unsigned)(~i);
            }
        }
    }
    gbar(bar, 2, true);

    // ---------- P4: exact rank + decode into sbox; zero-fill pad ranks ----------
    unsigned cnt = ctrl[3];
    int C = (int)(cnt < (unsigned)CAP ? cnt : (unsigned)CAP);
    if (bid * 256 < C) {                           // block-uniform participation
        int t = bid * 256 + tid;
        u64 mykey = (t < C) ? cand[t] : ~0ull;
        int rank = 0;
        for (int j0 = 0; j0 < C; j0 += 256) {
            int j = j0 + tid;
            tile[tid] = (j < C) ? cand[j] : 0ull;
            __syncthreads();
            int lim = (C - j0 < 256) ? (C - j0) : 256;
            #pragma unroll 4
            for (int jj = 0; jj < lim; ++jj) rank += (tile[jj] > mykey) ? 1 : 0;
            __syncthreads();
        }
        if (t < C && rank < TOPK) {
            int idx = (int)(~(unsigned)mykey);
            float4 box; bool v;
            decode_one(idx, delta, &box, &v);
            sbox[rank] = box;
        }
    }
    int nv = C < TOPK ? C : TOPK;
    {
        int r = bid * 256 + tid;                   // GRID*256 = 65536 >= KPAD
        if (r >= nv && r < KPAD) sbox[r] = make_float4(0.f, 0.f, 0.f, 0.f);
    }
    gbar(bar, 3, true);

    // ---------- P5: suppression bitmask, ROW-major mask[r*NW+cb], upper tri ----------
    for (int tix = bid; tix < 188 * 47; tix += GRID) {
        int rb = tix / 47;
        int cb0 = (tix % 47) * 4;
        if (cb0 + 3 < rb) continue;                // block-uniform skip
        __syncthreads();
        cbox[tid] = sbox[cb0 * 64 + tid];
        __syncthreads();
        int cb = cb0 + wave;
        if (cb >= rb) {
            int r = rb * 64 + lane;
            float4 me = sbox[r];
            float areaMe = (me.z - me.x) * (me.w - me.y);
            u64 bits = 0ull;
            for (int j = 0; j < 64; ++j) {
                float4 o = cbox[wave * 64 + j];
                float xx0 = fmaxf(me.x, o.x);
                float yy0 = fmaxf(me.y, o.y);
                float xx1 = fminf(me.z, o.z);
                float yy1 = fminf(me.w, o.w);
                float iw = fmaxf(xx1 - xx0, 0.f);
                float ih = fmaxf(yy1 - yy0, 0.f);
                float inter = iw * ih;
                float areaO = (o.z - o.x) * (o.w - o.y);
                float denom = fmaxf(areaMe + areaO - inter, 1e-8f);
                float iou = inter / denom;
                if (iou > 0.7f && (cb * 64 + j) != r) bits |= (1ull << j);
            }
            mask[(size_t)r * NW + cb] = bits;
        }
    }
    gbar(bar, 4, bid == 0);                        // only block 0 waits
    if (bid != 0) return;

    // ---------- P6: blocked greedy reduce (block 0), deferred 16-deep fold ----------
    int nblocks = (nv + 63) >> 6;
    u64 removed_t = ~0ull;                         // thread t owns column word t
    if (tid < NW) {
        long long lo = (long long)tid * 64;
        if (lo + 64 <= (long long)nv) removed_t = 0ull;
        else if (lo < (long long)nv)
            removed_t = ~((1ull << (unsigned)(nv - lo)) - 1ull);
    }

    int nk = 0;
    u64 p0=0,p1=0,p2=0,p3=0,p4=0,p5=0,p6=0,p7=0;
    u64 p8=0,p9=0,p10=0,p11=0,p12=0,p13=0,p14=0,p15=0;
    u64 dgnext = 0ull;
    if (nblocks > 0) dgnext = mask[(size_t)lane * NW + 0];  // diag of block 0

    for (int b = 0; b < nblocks; ++b) {
        // fold pending OR loads (issued last iteration; coalesced strips)
        removed_t |= ((p0|p1)|(p2|p3)) | ((p4|p5)|(p6|p7));
        removed_t |= ((p8|p9)|(p10|p11)) | ((p12|p13)|(p14|p15));
        p0=p1=p2=p3=p4=p5=p6=p7=0ull;
        p8=p9=p10=p11=p12=p13=p14=p15=0ull;
        u64 dg = dgnext;
        if (tid == b) s_rw[b & 1] = removed_t;     // word b now final
        __syncthreads();
        u64 rw = s_rw[b & 1];
        if (b + 1 < nblocks)                       // prefetch next diag
            dgnext = mask[(size_t)((b + 1) * 64 + lane) * NW + (b + 1)];

        // resolve via IoU symmetry: lane tests bits of ITS OWN diag word
        bool alive = ((rw >> lane) & 1ull) == 0ull;
        int budget = OUTN - nk;
        u64 keptmask = 0ull;
        int kc = 0;
        while (kc < budget) {
            u64 m = __ballot(alive);
            if (!m) break;
            int j = __ffsll(m) - 1;                // uniform
            keptmask |= (1ull << j);
            ++kc;
            alive = alive && (lane != j) && (((dg >> j) & 1ull) == 0ull);
        }

        if (wave == 0 && ((keptmask >> lane) & 1ull)) {
            int pos = nk + (int)__popcll(keptmask & ((1ull << lane) - 1ull));
            out[pos] = sbox[b * 64 + lane];
        }
        nk += kc;
        if (nk >= OUTN) break;

        // issue OR loads for next-iteration fold: mask[row*NW + tid] is
        // CONTIGUOUS across threads (coalesced strip per kept row)
        if (kc > 0 && tid > b && tid < NW) {
            const u64* mt = mask + tid;
            u64 km = keptmask;
            int jf = __ffsll(km) - 1;
            int i0 = jf;                          km &= km - 1;
            int i1  = km ? __ffsll(km) - 1 : jf;  km &= km - 1;
            int i2  = km ? __ffsll(km) - 1 : jf;  km &= km - 1;
            int i3  = km ? __ffsll(km) - 1 : jf;  km &= km - 1;
            int i4  = km ? __ffsll(km) - 1 : jf;  km &= km - 1;
            int i5  = km ? __ffsll(km) - 1 : jf;  km &= km - 1;
            int i6  = km ? __ffsll(km) - 1 : jf;  km &= km - 1;
            int i7  = km ? __ffsll(km) - 1 : jf;  km &= km - 1;
            int i8  = km ? __ffsll(km) - 1 : jf;  km &= km - 1;
            int i9  = km ? __ffsll(km) - 1 : jf;  km &= km - 1;
            int i10 = km ? __ffsll(km) - 1 : jf;  km &= km - 1;
            int i11 = km ? __ffsll(km) - 1 : jf;  km &= km - 1;
            int i12 = km ? __ffsll(km) - 1 : jf;  km &= km - 1;
            int i13 = km ? __ffsll(km) - 1 : jf;  km &= km - 1;
            int i14 = km ? __ffsll(km) - 1 : jf;  km &= km - 1;
            int i15 = km ? __ffsll(km) - 1 : jf;  km &= km - 1;
            size_t rb8 = (size_t)b * 64 * NW;
            p0  = mt[rb8 + (size_t)i0  * NW];
            p1  = mt[rb8 + (size_t)i1  * NW];
            p2  = mt[rb8 + (size_t)i2  * NW];
            p3  = mt[rb8 + (size_t)i3  * NW];
            p4  = mt[rb8 + (size_t)i4  * NW];
            p5  = mt[rb8 + (size_t)i5  * NW];
            p6  = mt[rb8 + (size_t)i6  * NW];
            p7  = mt[rb8 + (size_t)i7  * NW];
            p8  = mt[rb8 + (size_t)i8  * NW];
            p9  = mt[rb8 + (size_t)i9  * NW];
            p10 = mt[rb8 + (size_t)i10 * NW];
            p11 = mt[rb8 + (size_t)i11 * NW];
            p12 = mt[rb8 + (size_t)i12 * NW];
            p13 = mt[rb8 + (size_t)i13 * NW];
            p14 = mt[rb8 + (size_t)i14 * NW];
            p15 = mt[rb8 + (size_t)i15 * NW];
            while (km) {                           // rare: kc > 16
                int j = __ffsll(km) - 1; km &= km - 1;
                removed_t |= mt[rb8 + (size_t)j * NW];
            }
        }
    }

    float4 z = make_float4(0.f, 0.f, 0.f, 0.f);
    for (int p = nk + tid; p < OUTN; p += 256) out[p] = z;
}

extern "C" void kernel_launch(void* const* d_in, const int* in_sizes, int n_in,
                              void* d_out, int out_size, void* d_ws, size_t ws_size,
                              hipStream_t stream) {
    const float4* delta = (const float4*)d_in[0];
    const float2* score = (const float2*)d_in[1];
    char* ws = (char*)d_ws;

    // Workspace layout (bytes)
    unsigned* ukey  = (unsigned*)(ws + 0);         // N_ANCH u32
    u64*      cand  = (u64*)(ws + 2359296);        // CAP u64
    unsigned* hist1 = (unsigned*)(ws + 2621440);   // 256 u32  -- memset region start
    unsigned* hist2 = (unsigned*)(ws + 2622464);   // 256 u32
    unsigned* ctrl  = (unsigned*)(ws + 2623488);   // 16 u32
    unsigned* bar   = (unsigned*)(ws + 2623552);   // 5 slots x 128B = 640B
    float4*   sbox  = (float4*)(ws + 2624192);     // KPAD float4 (pad zeroed in-kernel)
    u64*      mask  = (u64*)(ws + 2816704);        // KPAD*NW u64, ROW-major
    float4*   outp  = (float4*)d_out;

    hipMemsetAsync(ws + 2621440, 0, 2752, stream); // hist1+hist2+ctrl+bar

    void* args[] = {&delta, &score, &ukey, &hist1, &hist2, &ctrl, &bar,
                    &cand, &sbox, &mask, &outp};
    hipLaunchCooperativeKernel((const void*)k_fused, dim3(GRID), dim3(256),
                               args, 0, stream);
}